// Round 2
// baseline (15068.633 us; speedup 1.0000x reference)
//
#include <hip/hip_runtime.h>
#include <hip/hip_bf16.h>

// Dims: S=512, B=32, I=768, H=256, NH=8, HD=32, ML=512
#define SDIM 512
#define BDIM 32

__device__ __forceinline__ float b2f(ushort u) {
    union { uint32_t i; float f; } v; v.i = ((uint32_t)u) << 16; return v.f;
}
__device__ __forceinline__ ushort f2b(float f) {
    union { float f; uint32_t i; } v; v.f = f;
    uint32_t u = v.i;
    return (ushort)((u + 0x7fffu + ((u >> 16) & 1u)) >> 16);  // RNE
}

// ---------------------------------------------------------------------------
// [R,C] -> [C,R] fp32 transpose (LDS tiled). Grid: (C/32, R/32), 256 threads.
// ---------------------------------------------------------------------------
__global__ __launch_bounds__(256) void transpose_kernel(
    const float* __restrict__ src, float* __restrict__ dst, int R, int C)
{
    __shared__ float t[32][33];
    const int bx = blockIdx.x * 32, by = blockIdx.y * 32;
    const int x = threadIdx.x & 31, y = threadIdx.x >> 5;   // y: 0..7
    #pragma unroll
    for (int dy = 0; dy < 32; dy += 8)
        t[y + dy][x] = src[(size_t)(by + y + dy) * C + bx + x];
    __syncthreads();
    #pragma unroll
    for (int dy = 0; dy < 32; dy += 8)
        dst[(size_t)(bx + y + dy) * R + by + x] = t[x][y + dy];
}

// ---------------------------------------------------------------------------
// C[m,n] = sum_k A[m,k]*B[n,k] + bias[n] (+ relpos for K-proj).
// ABF16: A is bf16 (h_ner/h_re). ASWAP: A row [s*B+b] while m = b*S+s.
// ---------------------------------------------------------------------------
template<bool ABF16, bool ASWAP, bool RELPOS>
__global__ __launch_bounds__(256) void gemm_kernel(
    const void* __restrict__ Av, const float* __restrict__ Bw,
    const float* __restrict__ bias, const float* __restrict__ rp,
    float* __restrict__ C, int M, int N, int K)
{
    __shared__ float As[16][68];
    __shared__ float Bs[16][68];
    const int tid = threadIdx.x;
    const int tile_m = blockIdx.x * 64, tile_n = blockIdx.y * 64;
    const int lr = tid >> 2;            // 0..63: row within tile
    const int lk = (tid & 3) * 4;       // 0,4,8,12
    const int am = tile_m + lr;
    const int ar = ASWAP ? ((am & (SDIM - 1)) * BDIM + (am >> 9)) : am;
    const int bn = tile_n + lr;
    const int ty = tid >> 4, tx = tid & 15;
    float acc[4][4] = {};

    for (int k0 = 0; k0 < K; k0 += 16) {
        float f0, f1, f2, f3;
        if constexpr (ABF16) {
            ushort4 u = *(const ushort4*)((const ushort*)Av + (size_t)ar * K + k0 + lk);
            f0 = b2f(u.x); f1 = b2f(u.y); f2 = b2f(u.z); f3 = b2f(u.w);
        } else {
            float4 u = *(const float4*)((const float*)Av + (size_t)ar * K + k0 + lk);
            f0 = u.x; f1 = u.y; f2 = u.z; f3 = u.w;
        }
        As[lk + 0][lr] = f0; As[lk + 1][lr] = f1; As[lk + 2][lr] = f2; As[lk + 3][lr] = f3;
        float4 v = *(const float4*)(Bw + (size_t)bn * K + k0 + lk);
        Bs[lk + 0][lr] = v.x; Bs[lk + 1][lr] = v.y;
        Bs[lk + 2][lr] = v.z; Bs[lk + 3][lr] = v.w;
        __syncthreads();
        #pragma unroll
        for (int k = 0; k < 16; k++) {
            float4 a4 = *(const float4*)&As[k][ty * 4];
            float4 b4 = *(const float4*)&Bs[k][tx * 4];
            float av[4] = {a4.x, a4.y, a4.z, a4.w};
            float bv[4] = {b4.x, b4.y, b4.z, b4.w};
            #pragma unroll
            for (int j = 0; j < 4; j++)
                #pragma unroll
                for (int i = 0; i < 4; i++)
                    acc[j][i] += av[j] * bv[i];
        }
        __syncthreads();
    }
    #pragma unroll
    for (int j = 0; j < 4; j++) {
        const int gm = tile_m + ty * 4 + j;
        const int sgm = gm & (SDIM - 1);
        float4 o;
        float* op = &o.x;
        #pragma unroll
        for (int i = 0; i < 4; i++) {
            const int gn = tile_n + tx * 4 + i;
            float v = acc[j][i] + bias[gn];
            if (RELPOS) v += rp[((gn >> 5) << 14) + (sgm << 5) + (gn & 31)];
            op[i] = v;
        }
        *(float4*)(C + (size_t)gm * N + tile_n + tx * 4) = o;
    }
}

// ---------------------------------------------------------------------------
// Sequential PFN scan. One workgroup (1024 thr) per batch element.
// WhT = Wh^T [256,1280], WtT = Wt^T [768,256]: GEMV loads are lane-coalesced.
// ---------------------------------------------------------------------------
__global__ __launch_bounds__(1024) void scan_kernel(
    const float* __restrict__ gx,   // [S,B,1280] precomputed x@Wi.T+bi
    const float* __restrict__ WhT,  // [256,1280]
    const float* __restrict__ bh,   // [1280]
    const float* __restrict__ WtT,  // [768,256]
    const float* __restrict__ bt,   // [256]
    ushort* __restrict__ h_ner,     // [S,B,256] bf16
    ushort* __restrict__ h_re)      // [S,B,256] bf16
{
    const int b = blockIdx.x;
    const int tid = threadIdx.x;
    __shared__ float hs[256], cs[256], g[1280], cat[768];
    __shared__ float rmax[16], rsum[16];
    if (tid < 256) { hs[tid] = 0.f; cs[tid] = 0.f; }
    __syncthreads();
    const int lane = tid & 63;
    const int ch = tid >> 8;            // cumsoftmax chunk 0..3
    const int wch = (tid >> 6) & 3;     // wave within chunk

    for (int t = 0; t < SDIM; t++) {
        const float* gxr = gx + (size_t)(t * BDIM + b) * 1280;
        // ---- gates = gx + bh + h @ Wh.T (coalesced via WhT) ----
        {
            float a1 = 0.f;
            const float* wcol = WhT + tid;
            #pragma unroll 2
            for (int k = 0; k < 256; k += 4) {
                float4 h4 = *(const float4*)&hs[k];
                a1 += h4.x * wcol[(k + 0) * 1280] + h4.y * wcol[(k + 1) * 1280]
                    + h4.z * wcol[(k + 2) * 1280] + h4.w * wcol[(k + 3) * 1280];
            }
            g[tid] = gxr[tid] + bh[tid] + a1;
            if (tid < 256) {
                float a2 = 0.f;
                const float* wcol2 = WhT + 1024 + tid;
                #pragma unroll 2
                for (int k = 0; k < 256; k += 4) {
                    float4 h4 = *(const float4*)&hs[k];
                    a2 += h4.x * wcol2[(k + 0) * 1280] + h4.y * wcol2[(k + 1) * 1280]
                        + h4.z * wcol2[(k + 2) * 1280] + h4.w * wcol2[(k + 3) * 1280];
                }
                g[1024 + tid] = gxr[1024 + tid] + bh[1024 + tid] + a2;
            }
        }
        __syncthreads();
        // ---- c = tanh(chunk0); cumsoftmax on chunks 1..4 (in place) ----
        if (tid < 256) g[tid] = tanhf(g[tid]);
        float v = g[256 + tid];
        float mx = v;
        #pragma unroll
        for (int off = 32; off >= 1; off >>= 1) mx = fmaxf(mx, __shfl_xor(mx, off, 64));
        if (lane == 0) rmax[ch * 4 + wch] = mx;
        __syncthreads();
        const float cmax = fmaxf(fmaxf(rmax[ch * 4], rmax[ch * 4 + 1]),
                                 fmaxf(rmax[ch * 4 + 2], rmax[ch * 4 + 3]));
        const float e = __expf(v - cmax);
        float wsum = e;
        #pragma unroll
        for (int off = 32; off >= 1; off >>= 1) wsum += __shfl_xor(wsum, off, 64);
        if (lane == 0) rsum[ch * 4 + wch] = wsum;
        float cum = e;   // inclusive wave scan
        #pragma unroll
        for (int off = 1; off <= 32; off <<= 1) {
            float tsh = __shfl_up(cum, (unsigned)off, 64);
            if (lane >= off) cum += tsh;
        }
        __syncthreads();
        const float tot = rsum[ch * 4] + rsum[ch * 4 + 1] + rsum[ch * 4 + 2] + rsum[ch * 4 + 3];
        float prev = 0.f;
        if (wch > 0) prev += rsum[ch * 4];
        if (wch > 1) prev += rsum[ch * 4 + 1];
        if (wch > 2) prev += rsum[ch * 4 + 2];
        float r = (cum + prev) / tot;
        if (ch == 0 || ch == 2) r = 1.f - r;   // eg_* = 1 - cumsoftmax
        g[256 + tid] = r;
        __syncthreads();
        // ---- combine gates -> c_re, c_ner, share; emit h_ner/h_re (bf16) ----
        if (tid < 256) {
            const float c = g[tid];
            const float egi = g[256 + tid], rgi = g[512 + tid];
            const float egc = g[768 + tid], rgc = g[1024 + tid];
            const float cin = cs[tid];
            const float ovc = rgc * egc, upc = rgc - ovc, dnc = egc - ovc;
            const float ovi = rgi * egi, upi = rgi - ovi, dni = egi - ovi;
            const float share = ovi * cin + ovc * c;
            const float cre = upi * cin + upc * c + share;
            const float cner = dni * cin + dnc * c + share;
            cat[tid] = cre; cat[256 + tid] = cner; cat[512 + tid] = share;
            const size_t ob = (size_t)(t * BDIM + b) * 256 + tid;
            h_re[ob] = f2b(tanhf(cre));
            h_ner[ob] = f2b(tanhf(cner));
        }
        __syncthreads();
        // ---- c_out = cat @ Wt.T + bt (4 k-partials per output via WtT) ----
        {
            const int j = tid & 255, part = tid >> 8;
            const float* wcol = WtT + (size_t)(part * 192) * 256 + j;
            const float* cp = cat + part * 192;
            float s = 0.f;
            #pragma unroll 2
            for (int k = 0; k < 192; k += 4) {
                float4 c4 = *(const float4*)&cp[k];
                s += c4.x * wcol[(k + 0) * 256] + c4.y * wcol[(k + 1) * 256]
                   + c4.z * wcol[(k + 2) * 256] + c4.w * wcol[(k + 3) * 256];
            }
            g[part * 256 + j] = s;
        }
        __syncthreads();
        if (tid < 256) {
            const float co = g[tid] + g[256 + tid] + g[512 + tid] + g[768 + tid] + bt[tid];
            cs[tid] = co;
            hs[tid] = tanhf(co);
        }
        __syncthreads();
    }
}

// ---------------------------------------------------------------------------
// Attention for one (b, head): scores = q·(k+relpos) (relpos pre-folded into
// kk_ws), softmax, PV. Each thread owns one ki row of K in registers.
// ---------------------------------------------------------------------------
__global__ __launch_bounds__(512) void attn_kernel(
    const float* __restrict__ q_ws, const float* __restrict__ kk_ws,
    const float* __restrict__ v_ws, float* __restrict__ o_ws)
{
    __shared__ float sc[8 * 516];   // 8 q-rows x 512 probs, stride 516 (bank pad)
    __shared__ float ps[8 * 256];   // PV partials per wave
    __shared__ float sinv[8];
    const int bn = blockIdx.x;
    const int b = bn >> 3, n = bn & 7;
    const int tid = threadIdx.x;
    const int w = tid >> 6, lane = tid & 63;
    const int ki = w * 64 + lane;
    float kv[32];
    {
        const float4* kp = (const float4*)(kk_ws + (size_t)(b * 512 + ki) * 256 + n * 32);
        #pragma unroll
        for (int d4 = 0; d4 < 8; d4++) {
            float4 x = kp[d4];
            kv[4 * d4] = x.x; kv[4 * d4 + 1] = x.y; kv[4 * d4 + 2] = x.z; kv[4 * d4 + 3] = x.w;
        }
    }
    const int rr = lane >> 3, dq = lane & 7;

    for (int q0 = 0; q0 < 512; q0 += 8) {
        const float* qbase = q_ws + (size_t)(b * 512 + q0) * 256 + n * 32;
        #pragma unroll 1
        for (int r = 0; r < 8; r++) {
            const float* qr = qbase + r * 256;   // wave-uniform address
            float s = 0.f;
            #pragma unroll
            for (int d = 0; d < 32; d++) s += qr[d] * kv[d];
            sc[r * 516 + ki] = s;
        }
        __syncthreads();
        // softmax of row w by wave w
        {
            float* row = sc + w * 516;
            float4 a = ((const float4*)row)[lane];
            float4 c4 = ((const float4*)row)[lane + 64];
            float mx = fmaxf(fmaxf(fmaxf(a.x, a.y), fmaxf(a.z, a.w)),
                             fmaxf(fmaxf(c4.x, c4.y), fmaxf(c4.z, c4.w)));
            #pragma unroll
            for (int off = 32; off >= 1; off >>= 1) mx = fmaxf(mx, __shfl_xor(mx, off, 64));
            a.x = __expf(a.x - mx); a.y = __expf(a.y - mx);
            a.z = __expf(a.z - mx); a.w = __expf(a.w - mx);
            c4.x = __expf(c4.x - mx); c4.y = __expf(c4.y - mx);
            c4.z = __expf(c4.z - mx); c4.w = __expf(c4.w - mx);
            float sm = a.x + a.y + a.z + a.w + c4.x + c4.y + c4.z + c4.w;
            #pragma unroll
            for (int off = 32; off >= 1; off >>= 1) sm += __shfl_xor(sm, off, 64);
            ((float4*)row)[lane] = a;
            ((float4*)row)[lane + 64] = c4;
            if (lane == 0) sinv[w] = 1.f / sm;
        }
        __syncthreads();
        // PV: wave w covers ki in [w*64, w*64+64); lane -> (row rr, 4 dims dq*4)
        {
            float4 acc = {0.f, 0.f, 0.f, 0.f};
            const float* erow = sc + rr * 516 + w * 64;
            const float* vbase = v_ws + (size_t)(b * 512 + w * 64) * 256 + n * 32 + dq * 4;
            #pragma unroll 8
            for (int j = 0; j < 64; j++) {
                const float e = erow[j];
                float4 vv = *(const float4*)(vbase + (size_t)j * 256);
                acc.x += e * vv.x; acc.y += e * vv.y; acc.z += e * vv.z; acc.w += e * vv.w;
            }
            ((float4*)ps)[tid] = acc;
        }
        __syncthreads();
        if (tid < 256) {
            const int r2 = tid >> 5, d = tid & 31;
            float s = 0.f;
            #pragma unroll
            for (int ww = 0; ww < 8; ww++) s += ps[ww * 256 + r2 * 32 + d];
            o_ws[(size_t)(b * 512 + q0 + r2) * 256 + n * 32 + d] = s * sinv[r2];
        }
        __syncthreads();
    }
}

// ---------------------------------------------------------------------------
// y = LN(hb + proj) -> fp32 output in [S,B,H] order (residual hb is bf16)
// ---------------------------------------------------------------------------
__global__ __launch_bounds__(256) void ln_kernel(
    const float* __restrict__ proj, const ushort* __restrict__ hsrc,
    const float* __restrict__ lng, const float* __restrict__ lnb,
    float* __restrict__ outp)
{
    const int m = blockIdx.x;           // b*512 + s
    const int j = threadIdx.x;
    const int b = m >> 9, s = m & 511;
    const size_t oidx = (size_t)(s * 32 + b) * 256 + j;
    const float y = proj[(size_t)m * 256 + j] + b2f(hsrc[oidx]);
    float sum = y, sq = y * y;
    #pragma unroll
    for (int off = 32; off >= 1; off >>= 1) {
        sum += __shfl_xor(sum, off, 64);
        sq += __shfl_xor(sq, off, 64);
    }
    __shared__ float r1[4], r2[4];
    const int wv = j >> 6;
    if ((j & 63) == 0) { r1[wv] = sum; r2[wv] = sq; }
    __syncthreads();
    const float ts = r1[0] + r1[1] + r1[2] + r1[3];
    const float tq = r2[0] + r2[1] + r2[2] + r2[3];
    const float mean = ts * (1.f / 256.f);
    const float var = tq * (1.f / 256.f) - mean * mean;
    const float o = (y - mean) * rsqrtf(var + 1e-5f) * lng[j] + lnb[j];
    outp[oidx] = o;
}

extern "C" void kernel_launch(void* const* d_in, const int* in_sizes, int n_in,
                              void* d_out, int out_size, void* d_ws, size_t ws_size,
                              hipStream_t stream) {
    (void)in_sizes; (void)n_in; (void)out_size; (void)ws_size;
    const float* x   = (const float*)d_in[0];
    const float* Wi  = (const float*)d_in[1];
    const float* bi  = (const float*)d_in[2];
    const float* Wh  = (const float*)d_in[3];
    const float* bh  = (const float*)d_in[4];
    const float* Wt  = (const float*)d_in[5];
    const float* bt  = (const float*)d_in[6];
    const float* Wq  = (const float*)d_in[7];
    const float* bq  = (const float*)d_in[8];
    const float* Wk  = (const float*)d_in[9];
    const float* bk  = (const float*)d_in[10];
    const float* Wv  = (const float*)d_in[11];
    const float* bv  = (const float*)d_in[12];
    const float* Wo  = (const float*)d_in[13];
    const float* bo  = (const float*)d_in[14];
    const float* rp  = (const float*)d_in[15];
    const float* lng = (const float*)d_in[16];
    const float* lnb = (const float*)d_in[17];
    float* outp = (float*)d_out;

    float* ws = (float*)d_ws;
    // pool [0, 20971520): gx fp32 [16384,1280] during scan; attn scratch after
    float* gx    = ws;
    float* q_ws  = ws;
    float* kk_ws = ws + 4194304;
    float* v_ws  = ws + 8388608;
    float* o_ws  = ws + 12582912;
    float* pj_ws = ws + 16777216;            // ends exactly at 20971520
    ushort* hner16 = (ushort*)(ws + 20971520);   // [S,B,256] bf16
    ushort* hre16  = (ushort*)(ws + 23068672);
    float* WhT = ws + 25165824;              // [256,1280] fp32
    float* WtT = ws + 25493504;              // [768,256] fp32
    // total: 25690112 floats = 102.8 MB

    // 0) transpose recurrent weights for coalesced scan GEMVs
    transpose_kernel<<<dim3(8, 40), 256, 0, stream>>>(Wh, WhT, 1280, 256);
    transpose_kernel<<<dim3(24, 8), 256, 0, stream>>>(Wt, WtT, 256, 768);

    // 1) gates_x = x @ Wi.T + bi   [16384,1280]
    gemm_kernel<false, false, false><<<dim3(256, 20), 256, 0, stream>>>(
        x, Wi, bi, nullptr, gx, 16384, 1280, 768);

    // 2) sequential scan (one block per batch element)
    scan_kernel<<<dim3(32), dim3(1024), 0, stream>>>(gx, WhT, bh, WtT, bt, hner16, hre16);

    // 3) three attentions: (h_ner,0), (h_re,1), (h_re,2)
    for (int i = 0; i < 3; i++) {
        const ushort* src16 = (i == 0) ? hner16 : hre16;
        gemm_kernel<true, true, false><<<dim3(256, 4), 256, 0, stream>>>(
            src16, Wq + (size_t)i * 65536, bq + i * 256, nullptr, q_ws, 16384, 256, 256);
        gemm_kernel<true, true, true><<<dim3(256, 4), 256, 0, stream>>>(
            src16, Wk + (size_t)i * 65536, bk + i * 256, rp + (size_t)i * 131072, kk_ws, 16384, 256, 256);
        gemm_kernel<true, true, false><<<dim3(256, 4), 256, 0, stream>>>(
            src16, Wv + (size_t)i * 65536, bv + i * 256, nullptr, v_ws, 16384, 256, 256);
        attn_kernel<<<dim3(256), dim3(512), 0, stream>>>(q_ws, kk_ws, v_ws, o_ws);
        gemm_kernel<false, false, false><<<dim3(256, 4), 256, 0, stream>>>(
            o_ws, Wo + (size_t)i * 65536, bo + i * 256, nullptr, pj_ws, 16384, 256, 256);
        ln_kernel<<<dim3(16384), dim3(256), 0, stream>>>(
            pj_ws, src16, lng, lnb, outp + (size_t)i * 4194304);
    }
}

// Round 3
// 9555.082 us; speedup vs baseline: 1.5770x; 1.5770x over previous
//
#include <hip/hip_runtime.h>
#include <hip/hip_bf16.h>

// Dims: S=512, B=32, I=768, H=256, NH=8, HD=32, ML=512
#define SDIM 512
#define BDIM 32

__device__ __forceinline__ float b2f(ushort u) {
    union { uint32_t i; float f; } v; v.i = ((uint32_t)u) << 16; return v.f;
}
__device__ __forceinline__ ushort f2b(float f) {
    union { float f; uint32_t i; } v; v.f = f;
    uint32_t u = v.i;
    return (ushort)((u + 0x7fffu + ((u >> 16) & 1u)) >> 16);  // RNE
}
// packed bf16 pair (lo = even k, hi = odd k)
__device__ __forceinline__ float plo(uint32_t u) {
    union { uint32_t i; float f; } v; v.i = u << 16; return v.f;
}
__device__ __forceinline__ float phi(uint32_t u) {
    union { uint32_t i; float f; } v; v.i = u & 0xffff0000u; return v.f;
}

// ---------------------------------------------------------------------------
// [R,C] -> [C,R] fp32 transpose (LDS tiled). Grid: (C/32, R/32), 256 threads.
// ---------------------------------------------------------------------------
__global__ __launch_bounds__(256) void transpose_kernel(
    const float* __restrict__ src, float* __restrict__ dst, int R, int C)
{
    __shared__ float t[32][33];
    const int bx = blockIdx.x * 32, by = blockIdx.y * 32;
    const int x = threadIdx.x & 31, y = threadIdx.x >> 5;   // y: 0..7
    #pragma unroll
    for (int dy = 0; dy < 32; dy += 8)
        t[y + dy][x] = src[(size_t)(by + y + dy) * C + bx + x];
    __syncthreads();
    #pragma unroll
    for (int dy = 0; dy < 32; dy += 8)
        dst[(size_t)(bx + y + dy) * R + by + x] = t[x][y + dy];
}

// ---------------------------------------------------------------------------
// Pack k-major fp32 [2P, J] into bf16-pair uint32 [P, J]:
//   out[p*J + j] = bf16(in[(2p+1)*J + j]) << 16 | bf16(in[2p*J + j])
// ---------------------------------------------------------------------------
__global__ __launch_bounds__(256) void pack_kernel(
    const float* __restrict__ in, uint32_t* __restrict__ out, int P, int J)
{
    const int idx = blockIdx.x * 256 + threadIdx.x;
    if (idx >= P * J) return;
    const int p = idx / J, j = idx - p * J;
    const ushort lo = f2b(in[(size_t)(2 * p) * J + j]);
    const ushort hi = f2b(in[(size_t)(2 * p + 1) * J + j]);
    out[idx] = ((uint32_t)hi << 16) | lo;
}

// ---------------------------------------------------------------------------
// C[m,n] = sum_k A[m,k]*B[n,k] + bias[n] (+ relpos for K-proj).
// ABF16: A is bf16 (h_ner/h_re). ASWAP: A row [s*B+b] while m = b*S+s.
// ---------------------------------------------------------------------------
template<bool ABF16, bool ASWAP, bool RELPOS>
__global__ __launch_bounds__(256) void gemm_kernel(
    const void* __restrict__ Av, const float* __restrict__ Bw,
    const float* __restrict__ bias, const float* __restrict__ rp,
    float* __restrict__ C, int M, int N, int K)
{
    __shared__ float As[16][68];
    __shared__ float Bs[16][68];
    const int tid = threadIdx.x;
    const int tile_m = blockIdx.x * 64, tile_n = blockIdx.y * 64;
    const int lr = tid >> 2;            // 0..63: row within tile
    const int lk = (tid & 3) * 4;       // 0,4,8,12
    const int am = tile_m + lr;
    const int ar = ASWAP ? ((am & (SDIM - 1)) * BDIM + (am >> 9)) : am;
    const int bn = tile_n + lr;
    const int ty = tid >> 4, tx = tid & 15;
    float acc[4][4] = {};

    for (int k0 = 0; k0 < K; k0 += 16) {
        float f0, f1, f2, f3;
        if constexpr (ABF16) {
            ushort4 u = *(const ushort4*)((const ushort*)Av + (size_t)ar * K + k0 + lk);
            f0 = b2f(u.x); f1 = b2f(u.y); f2 = b2f(u.z); f3 = b2f(u.w);
        } else {
            float4 u = *(const float4*)((const float*)Av + (size_t)ar * K + k0 + lk);
            f0 = u.x; f1 = u.y; f2 = u.z; f3 = u.w;
        }
        As[lk + 0][lr] = f0; As[lk + 1][lr] = f1; As[lk + 2][lr] = f2; As[lk + 3][lr] = f3;
        float4 v = *(const float4*)(Bw + (size_t)bn * K + k0 + lk);
        Bs[lk + 0][lr] = v.x; Bs[lk + 1][lr] = v.y;
        Bs[lk + 2][lr] = v.z; Bs[lk + 3][lr] = v.w;
        __syncthreads();
        #pragma unroll
        for (int k = 0; k < 16; k++) {
            float4 a4 = *(const float4*)&As[k][ty * 4];
            float4 b4 = *(const float4*)&Bs[k][tx * 4];
            float av[4] = {a4.x, a4.y, a4.z, a4.w};
            float bv[4] = {b4.x, b4.y, b4.z, b4.w};
            #pragma unroll
            for (int j = 0; j < 4; j++)
                #pragma unroll
                for (int i = 0; i < 4; i++)
                    acc[j][i] += av[j] * bv[i];
        }
        __syncthreads();
    }
    #pragma unroll
    for (int j = 0; j < 4; j++) {
        const int gm = tile_m + ty * 4 + j;
        const int sgm = gm & (SDIM - 1);
        float4 o;
        float* op = &o.x;
        #pragma unroll
        for (int i = 0; i < 4; i++) {
            const int gn = tile_n + tx * 4 + i;
            float v = acc[j][i] + bias[gn];
            if (RELPOS) v += rp[((gn >> 5) << 14) + (sgm << 5) + (gn & 31)];
            op[i] = v;
        }
        *(float4*)(C + (size_t)gm * N + tile_n + tx * 4) = o;
    }
}

// 8 bf16-pairs (16 k) against 16 h floats from LDS
#define CHUNK8(WP, STRIDE, HP, ACC)                                            \
    {                                                                          \
        uint32_t w0 = (WP)[(size_t)(0) * (STRIDE)];                            \
        uint32_t w1 = (WP)[(size_t)(1) * (STRIDE)];                            \
        uint32_t w2 = (WP)[(size_t)(2) * (STRIDE)];                            \
        uint32_t w3 = (WP)[(size_t)(3) * (STRIDE)];                            \
        uint32_t w4 = (WP)[(size_t)(4) * (STRIDE)];                            \
        uint32_t w5 = (WP)[(size_t)(5) * (STRIDE)];                            \
        uint32_t w6 = (WP)[(size_t)(6) * (STRIDE)];                            \
        uint32_t w7 = (WP)[(size_t)(7) * (STRIDE)];                            \
        float4 h0 = *(const float4*)((HP) + 0);                                \
        float4 h1 = *(const float4*)((HP) + 4);                                \
        float4 h2 = *(const float4*)((HP) + 8);                                \
        float4 h3 = *(const float4*)((HP) + 12);                               \
        ACC += plo(w0) * h0.x + phi(w0) * h0.y + plo(w1) * h0.z + phi(w1) * h0.w; \
        ACC += plo(w2) * h1.x + phi(w2) * h1.y + plo(w3) * h1.z + phi(w3) * h1.w; \
        ACC += plo(w4) * h2.x + phi(w4) * h2.y + plo(w5) * h2.z + phi(w5) * h2.w; \
        ACC += plo(w6) * h3.x + phi(w6) * h3.y + plo(w7) * h3.z + phi(w7) * h3.w; \
    }

// ---------------------------------------------------------------------------
// Sequential PFN scan. One workgroup (1024 thr) per batch element.
// Weights are bf16-pair packed, k-major: Wh2 [128][1280], Wt2 [384][256].
// Per-CU L2 weight traffic: 1.05 MB/step (was 2.1 MB fp32).
// ---------------------------------------------------------------------------
__global__ __launch_bounds__(1024) void scan_kernel(
    const float* __restrict__ gx,       // [S,B,1280] precomputed x@Wi.T+bi
    const uint32_t* __restrict__ Wh2,   // [128,1280] bf16 pairs over k
    const float* __restrict__ bh,       // [1280]
    const uint32_t* __restrict__ Wt2,   // [384,256] bf16 pairs over k
    const float* __restrict__ bt,       // [256]
    ushort* __restrict__ h_ner,         // [S,B,256] bf16
    ushort* __restrict__ h_re)          // [S,B,256] bf16
{
    const int b = blockIdx.x;
    const int tid = threadIdx.x;
    __shared__ float hs[256], cs[256], g[1280], cat[768], ext[1024];
    __shared__ float rmax[16], rsum[16];
    if (tid < 256) { hs[tid] = 0.f; cs[tid] = 0.f; }
    __syncthreads();
    const int lane = tid & 63;
    const int ch = tid >> 8;            // cumsoftmax chunk 0..3
    const int wch = (tid >> 6) & 3;     // wave within chunk
    const int er = tid & 255;           // extra-row id / GEMV2 output id
    const int ep = tid >> 8;            // k-part 0..3

    for (int t = 0; t < SDIM; t++) {
        const float* gxr = gx + (size_t)(t * BDIM + b) * 1280;
        // ---- gates = gx + bh + h @ Wh.T ----
        // main: rows 0..1023 (row j = tid, full k)
        {
            float a1 = 0.f;
            const uint32_t* wc = Wh2 + tid;
            #pragma unroll 2
            for (int p0 = 0; p0 < 128; p0 += 8)
                CHUNK8(wc + (size_t)p0 * 1280, 1280, hs + 2 * p0, a1);
            g[tid] = gxr[tid] + bh[tid] + a1;
        }
        // extra: rows 1024..1279, k split 4 ways (64 k = 8 pairs x 4 chunks)
        {
            float ae = 0.f;
            const uint32_t* wc = Wh2 + 1024 + er;
            const int pbase = ep * 32;
            #pragma unroll 2
            for (int i = 0; i < 32; i += 8)
                CHUNK8(wc + (size_t)(pbase + i) * 1280, 1280, hs + 2 * (pbase + i), ae);
            ext[ep * 256 + er] = ae;
        }
        __syncthreads();
        // ---- c = tanh(chunk0); cumsoftmax on chunks 1..4 (in place) ----
        if (tid < 256) g[tid] = tanhf(g[tid]);
        float v;
        if (tid >= 768) {   // these threads own gate rows 1024..1279: finish reduction
            const int r = tid - 768;
            v = gxr[1024 + r] + bh[1024 + r]
              + ext[r] + ext[256 + r] + ext[512 + r] + ext[768 + r];
        } else {
            v = g[256 + tid];
        }
        float mx = v;
        #pragma unroll
        for (int off = 32; off >= 1; off >>= 1) mx = fmaxf(mx, __shfl_xor(mx, off, 64));
        if (lane == 0) rmax[ch * 4 + wch] = mx;
        __syncthreads();
        const float cmax = fmaxf(fmaxf(rmax[ch * 4], rmax[ch * 4 + 1]),
                                 fmaxf(rmax[ch * 4 + 2], rmax[ch * 4 + 3]));
        const float e = __expf(v - cmax);
        float wsum = e;
        #pragma unroll
        for (int off = 32; off >= 1; off >>= 1) wsum += __shfl_xor(wsum, off, 64);
        if (lane == 0) rsum[ch * 4 + wch] = wsum;
        float cum = e;   // inclusive wave scan
        #pragma unroll
        for (int off = 1; off <= 32; off <<= 1) {
            float tsh = __shfl_up(cum, (unsigned)off, 64);
            if (lane >= off) cum += tsh;
        }
        __syncthreads();
        const float tot = rsum[ch * 4] + rsum[ch * 4 + 1] + rsum[ch * 4 + 2] + rsum[ch * 4 + 3];
        float prev = 0.f;
        if (wch > 0) prev += rsum[ch * 4];
        if (wch > 1) prev += rsum[ch * 4 + 1];
        if (wch > 2) prev += rsum[ch * 4 + 2];
        float r = (cum + prev) / tot;
        if (ch == 0 || ch == 2) r = 1.f - r;   // eg_* = 1 - cumsoftmax
        g[256 + tid] = r;
        __syncthreads();
        // ---- combine gates -> c_re, c_ner, share; emit h_ner/h_re (bf16) ----
        if (tid < 256) {
            const float c = g[tid];
            const float egi = g[256 + tid], rgi = g[512 + tid];
            const float egc = g[768 + tid], rgc = g[1024 + tid];
            const float cin = cs[tid];
            const float ovc = rgc * egc, upc = rgc - ovc, dnc = egc - ovc;
            const float ovi = rgi * egi, upi = rgi - ovi, dni = egi - ovi;
            const float share = ovi * cin + ovc * c;
            const float cre = upi * cin + upc * c + share;
            const float cner = dni * cin + dnc * c + share;
            cat[tid] = cre; cat[256 + tid] = cner; cat[512 + tid] = share;
            const size_t ob = (size_t)(t * BDIM + b) * 256 + tid;
            h_re[ob] = f2b(tanhf(cre));
            h_ner[ob] = f2b(tanhf(cner));
        }
        __syncthreads();
        // ---- c_out = cat @ Wt.T + bt (4 k-partials of 192 per output) ----
        {
            float s = 0.f;
            const uint32_t* wc = Wt2 + er;
            const int pbase = ep * 96;
            #pragma unroll 2
            for (int i = 0; i < 96; i += 8)
                CHUNK8(wc + (size_t)(pbase + i) * 256, 256, cat + 2 * (pbase + i), s);
            g[ep * 256 + er] = s;
        }
        __syncthreads();
        if (tid < 256) {
            const float co = g[tid] + g[256 + tid] + g[512 + tid] + g[768 + tid] + bt[tid];
            cs[tid] = co;
            hs[tid] = tanhf(co);
        }
        __syncthreads();
    }
}

// ---------------------------------------------------------------------------
// Attention for one (b, head): scores = q·(k+relpos) (relpos pre-folded into
// kk_ws), softmax, PV. Each thread owns one ki row of K in registers.
// ---------------------------------------------------------------------------
__global__ __launch_bounds__(512) void attn_kernel(
    const float* __restrict__ q_ws, const float* __restrict__ kk_ws,
    const float* __restrict__ v_ws, float* __restrict__ o_ws)
{
    __shared__ float sc[8 * 516];   // 8 q-rows x 512 probs, stride 516 (bank pad)
    __shared__ float ps[8 * 256];   // PV partials per wave
    __shared__ float sinv[8];
    const int bn = blockIdx.x;
    const int b = bn >> 3, n = bn & 7;
    const int tid = threadIdx.x;
    const int w = tid >> 6, lane = tid & 63;
    const int ki = w * 64 + lane;
    float kv[32];
    {
        const float4* kp = (const float4*)(kk_ws + (size_t)(b * 512 + ki) * 256 + n * 32);
        #pragma unroll
        for (int d4 = 0; d4 < 8; d4++) {
            float4 x = kp[d4];
            kv[4 * d4] = x.x; kv[4 * d4 + 1] = x.y; kv[4 * d4 + 2] = x.z; kv[4 * d4 + 3] = x.w;
        }
    }
    const int rr = lane >> 3, dq = lane & 7;

    for (int q0 = 0; q0 < 512; q0 += 8) {
        const float* qbase = q_ws + (size_t)(b * 512 + q0) * 256 + n * 32;
        #pragma unroll 1
        for (int r = 0; r < 8; r++) {
            const float* qr = qbase + r * 256;   // wave-uniform address
            float s = 0.f;
            #pragma unroll
            for (int d = 0; d < 32; d++) s += qr[d] * kv[d];
            sc[r * 516 + ki] = s;
        }
        __syncthreads();
        // softmax of row w by wave w
        {
            float* row = sc + w * 516;
            float4 a = ((const float4*)row)[lane];
            float4 c4 = ((const float4*)row)[lane + 64];
            float mx = fmaxf(fmaxf(fmaxf(a.x, a.y), fmaxf(a.z, a.w)),
                             fmaxf(fmaxf(c4.x, c4.y), fmaxf(c4.z, c4.w)));
            #pragma unroll
            for (int off = 32; off >= 1; off >>= 1) mx = fmaxf(mx, __shfl_xor(mx, off, 64));
            a.x = __expf(a.x - mx); a.y = __expf(a.y - mx);
            a.z = __expf(a.z - mx); a.w = __expf(a.w - mx);
            c4.x = __expf(c4.x - mx); c4.y = __expf(c4.y - mx);
            c4.z = __expf(c4.z - mx); c4.w = __expf(c4.w - mx);
            float sm = a.x + a.y + a.z + a.w + c4.x + c4.y + c4.z + c4.w;
            #pragma unroll
            for (int off = 32; off >= 1; off >>= 1) sm += __shfl_xor(sm, off, 64);
            ((float4*)row)[lane] = a;
            ((float4*)row)[lane + 64] = c4;
            if (lane == 0) sinv[w] = 1.f / sm;
        }
        __syncthreads();
        // PV: wave w covers ki in [w*64, w*64+64); lane -> (row rr, 4 dims dq*4)
        {
            float4 acc = {0.f, 0.f, 0.f, 0.f};
            const float* erow = sc + rr * 516 + w * 64;
            const float* vbase = v_ws + (size_t)(b * 512 + w * 64) * 256 + n * 32 + dq * 4;
            #pragma unroll 8
            for (int j = 0; j < 64; j++) {
                const float e = erow[j];
                float4 vv = *(const float4*)(vbase + (size_t)j * 256);
                acc.x += e * vv.x; acc.y += e * vv.y; acc.z += e * vv.z; acc.w += e * vv.w;
            }
            ((float4*)ps)[tid] = acc;
        }
        __syncthreads();
        if (tid < 256) {
            const int r2 = tid >> 5, d = tid & 31;
            float s = 0.f;
            #pragma unroll
            for (int ww = 0; ww < 8; ww++) s += ps[ww * 256 + r2 * 32 + d];
            o_ws[(size_t)(b * 512 + q0 + r2) * 256 + n * 32 + d] = s * sinv[r2];
        }
        __syncthreads();
    }
}

// ---------------------------------------------------------------------------
// y = LN(hb + proj) -> fp32 output in [S,B,H] order (residual hb is bf16)
// ---------------------------------------------------------------------------
__global__ __launch_bounds__(256) void ln_kernel(
    const float* __restrict__ proj, const ushort* __restrict__ hsrc,
    const float* __restrict__ lng, const float* __restrict__ lnb,
    float* __restrict__ outp)
{
    const int m = blockIdx.x;           // b*512 + s
    const int j = threadIdx.x;
    const int b = m >> 9, s = m & 511;
    const size_t oidx = (size_t)(s * 32 + b) * 256 + j;
    const float y = proj[(size_t)m * 256 + j] + b2f(hsrc[oidx]);
    float sum = y, sq = y * y;
    #pragma unroll
    for (int off = 32; off >= 1; off >>= 1) {
        sum += __shfl_xor(sum, off, 64);
        sq += __shfl_xor(sq, off, 64);
    }
    __shared__ float r1[4], r2[4];
    const int wv = j >> 6;
    if ((j & 63) == 0) { r1[wv] = sum; r2[wv] = sq; }
    __syncthreads();
    const float ts = r1[0] + r1[1] + r1[2] + r1[3];
    const float tq = r2[0] + r2[1] + r2[2] + r2[3];
    const float mean = ts * (1.f / 256.f);
    const float var = tq * (1.f / 256.f) - mean * mean;
    const float o = (y - mean) * rsqrtf(var + 1e-5f) * lng[j] + lnb[j];
    outp[oidx] = o;
}

extern "C" void kernel_launch(void* const* d_in, const int* in_sizes, int n_in,
                              void* d_out, int out_size, void* d_ws, size_t ws_size,
                              hipStream_t stream) {
    (void)in_sizes; (void)n_in; (void)out_size; (void)ws_size;
    const float* x   = (const float*)d_in[0];
    const float* Wi  = (const float*)d_in[1];
    const float* bi  = (const float*)d_in[2];
    const float* Wh  = (const float*)d_in[3];
    const float* bh  = (const float*)d_in[4];
    const float* Wt  = (const float*)d_in[5];
    const float* bt  = (const float*)d_in[6];
    const float* Wq  = (const float*)d_in[7];
    const float* bq  = (const float*)d_in[8];
    const float* Wk  = (const float*)d_in[9];
    const float* bk  = (const float*)d_in[10];
    const float* Wv  = (const float*)d_in[11];
    const float* bv  = (const float*)d_in[12];
    const float* Wo  = (const float*)d_in[13];
    const float* bo  = (const float*)d_in[14];
    const float* rp  = (const float*)d_in[15];
    const float* lng = (const float*)d_in[16];
    const float* lnb = (const float*)d_in[17];
    float* outp = (float*)d_out;

    float* ws = (float*)d_ws;
    // pool [0, 20971520): gx fp32 [16384,1280] during scan; attn scratch after
    float* gx    = ws;
    float* q_ws  = ws;
    float* kk_ws = ws + 4194304;
    float* v_ws  = ws + 8388608;
    float* o_ws  = ws + 12582912;
    float* pj_ws = ws + 16777216;            // ends exactly at 20971520
    ushort* hner16 = (ushort*)(ws + 20971520);   // [S,B,256] bf16
    ushort* hre16  = (ushort*)(ws + 23068672);
    float* WhT = ws + 25165824;              // [256,1280] fp32
    float* WtT = ws + 25493504;              // [768,256] fp32
    uint32_t* Wh2 = (uint32_t*)(ws + 25690112);  // [128,1280] bf16 pairs
    uint32_t* Wt2 = (uint32_t*)(ws + 25853952);  // [384,256] bf16 pairs
    // total: 25952256 floats = 103.8 MB

    // 0) transpose recurrent weights to k-major, then pack to bf16 pairs
    transpose_kernel<<<dim3(8, 40), 256, 0, stream>>>(Wh, WhT, 1280, 256);
    transpose_kernel<<<dim3(24, 8), 256, 0, stream>>>(Wt, WtT, 256, 768);
    pack_kernel<<<dim3(640), 256, 0, stream>>>(WhT, Wh2, 128, 1280);
    pack_kernel<<<dim3(384), 256, 0, stream>>>(WtT, Wt2, 384, 256);

    // 1) gates_x = x @ Wi.T + bi   [16384,1280]
    gemm_kernel<false, false, false><<<dim3(256, 20), 256, 0, stream>>>(
        x, Wi, bi, nullptr, gx, 16384, 1280, 768);

    // 2) sequential scan (one block per batch element)
    scan_kernel<<<dim3(32), dim3(1024), 0, stream>>>(gx, Wh2, bh, Wt2, bt, hner16, hre16);

    // 3) three attentions: (h_ner,0), (h_re,1), (h_re,2)
    for (int i = 0; i < 3; i++) {
        const ushort* src16 = (i == 0) ? hner16 : hre16;
        gemm_kernel<true, true, false><<<dim3(256, 4), 256, 0, stream>>>(
            src16, Wq + (size_t)i * 65536, bq + i * 256, nullptr, q_ws, 16384, 256, 256);
        gemm_kernel<true, true, true><<<dim3(256, 4), 256, 0, stream>>>(
            src16, Wk + (size_t)i * 65536, bk + i * 256, rp + (size_t)i * 131072, kk_ws, 16384, 256, 256);
        gemm_kernel<true, true, false><<<dim3(256, 4), 256, 0, stream>>>(
            src16, Wv + (size_t)i * 65536, bv + i * 256, nullptr, v_ws, 16384, 256, 256);
        attn_kernel<<<dim3(256), dim3(512), 0, stream>>>(q_ws, kk_ws, v_ws, o_ws);
        gemm_kernel<false, false, false><<<dim3(256, 4), 256, 0, stream>>>(
            o_ws, Wo + (size_t)i * 65536, bo + i * 256, nullptr, pj_ws, 16384, 256, 256);
        ln_kernel<<<dim3(16384), dim3(256), 0, stream>>>(
            pj_ws, src16, lng, lnb, outp + (size_t)i * 4194304);
    }
}